// Round 9
// baseline (119.222 us; speedup 1.0000x reference)
//
#include <hip/hip_runtime.h>
#include <hip/hip_bf16.h>
#include <stdint.h>

typedef __attribute__((ext_vector_type(8))) short short8;
typedef __attribute__((ext_vector_type(4))) float floatx4;
typedef __attribute__((ext_vector_type(4))) int intx4;

// ---------------------------------------------------------------------------
// Threefry-2x32 (20 rounds), bit-exact vs JAX (verified r2: absmax 0.0).
// ---------------------------------------------------------------------------
__device__ __forceinline__ void threefry2x32(uint32_t k0, uint32_t k1,
                                             uint32_t& x0, uint32_t& x1) {
  const uint32_t ks2 = k0 ^ k1 ^ 0x1BD11BDAu;
  uint32_t ks[3] = {k0, k1, ks2};
  const int rot[8] = {13, 15, 26, 6, 17, 29, 16, 24};
  x0 += ks[0];
  x1 += ks[1];
#pragma unroll
  for (int i = 0; i < 5; ++i) {
#pragma unroll
    for (int j = 0; j < 4; ++j) {
      const int r = rot[(i & 1) * 4 + j];
      x0 += x1;
      x1 = (x1 << r) | (x1 >> (32 - r));
      x1 ^= x0;
    }
    x0 += ks[(i + 1) % 3];
    x1 += ks[(i + 2) % 3] + (uint32_t)(i + 1);
  }
}

__device__ __forceinline__ float dropmask(int core, int e, float v) {
  uint32_t f0 = 0u, f1 = (uint32_t)core;
  threefry2x32(0u, 42u, f0, f1);
  uint32_t a = 0u, b = (uint32_t)e;
  threefry2x32(f0, f1, a, b);
  uint32_t bits = a ^ b;
  float u = __uint_as_float((bits >> 9) | 0x3F800000u) - 1.0f;
  float m = (u < 0.8f) ? 1.0f : 0.0f;
  return v * m / 0.8f;
}

__device__ __forceinline__ unsigned short f2bf(float f) {  // RNE
  uint32_t u = __float_as_uint(f);
  uint32_t r = u + 0x7fffu + ((u >> 16) & 1u);
  return (unsigned short)(r >> 16);
}

union B2I { __hip_bfloat162 b; int i; };
__device__ __forceinline__ int pk_bf16(float lo, float hi) {
  B2I u;
  u.b = __float22bfloat162_rn(make_float2(lo, hi));
  return u.i;
}
union Frag { intx4 i; short8 s; };

// ---------------------------------------------------------------------------
// Prep: masked bf16 B matrices, pre-swizzled into MFMA B-fragment order
// (verified r3-r8). stage1: k = c*32+q*8+j (c<16). stage2: t=45q+c, m=t/5,
// nk=8*(t%5)+j (c<45, K'=1440, zeros for nk>=36 or invalid col).
// Also zero-inits out (fused kernel accumulates with atomics).
// ---------------------------------------------------------------------------
__global__ void prep_kernel(const float* __restrict__ eps0,
                            const float* __restrict__ eps1,
                            unsigned short* __restrict__ bsw1,
                            unsigned short* __restrict__ bsw2,
                            float* __restrict__ out) {
  int idx = blockIdx.x * 256 + threadIdx.x;  // grid exactly 31232
  if (idx < 1280) out[idx] = 0.0f;
  if (idx < 8192) {
    int j = idx & 7, L = (idx >> 3) & 63, c = idx >> 9;
    int o = L & 15, q = L >> 4;
    int k = c * 32 + q * 8 + j;
    float v = 0.0f;
    if (o < 6) {
      int e = o * 512 + k;
      v = dropmask(0, e, eps0[e]);
    }
    bsw1[idx] = f2bf(v);
  } else {
    int t2 = idx - 8192;  // < 23040 = 45*512
    int j = t2 & 7, L = (t2 >> 3) & 63, c = t2 >> 9;
    int o = L & 15, q = L >> 4;
    int t = 45 * q + c;
    int m = t / 5, nk = 8 * (t % 5) + j;
    float v = 0.0f;
    if (o < 10 && nk < 36) {
      int e = o * 1296 + m * 36 + nk;
      v = dropmask(1, e, eps1[e]);
    }
    bsw2[t2] = f2bf(v);
  }
}

// 6-way select, cndmask chain (runtime k, constant element indices)
__device__ __forceinline__ float sel6(const float a[6], int k) {
  float r = a[0];
  r = (k == 1) ? a[1] : r;
  r = (k == 2) ? a[2] : r;
  r = (k == 3) ? a[3] : r;
  r = (k == 4) ? a[4] : r;
  r = (k == 5) ? a[5] : r;
  return r;
}

// ---------------------------------------------------------------------------
// Fused kernel, 4 blocks per image (grid 512, 512 thr = 8 waves).
// Quarter r covers stage2 rows {0-6,7-12,13-18,19-24}; h rows s0..s0+ns
// (1-row halo recomputed). h/flat quarter-tiles in LDS (~12.5 KB).
// B1 (16 frags) then B2 (45 frags) register-resident per wave; K-loops are
// pure VALU+MFMA. Linear fused: per-block partial + atomicAdd.
// ---------------------------------------------------------------------------
__global__ __launch_bounds__(512, 2) void fused_kernel(
    const float* __restrict__ x, const unsigned short* __restrict__ bsw1,
    const unsigned short* __restrict__ bsw2, const float* __restrict__ W,
    const float* __restrict__ bias, float* __restrict__ out) {
  __shared__ float h_lds[8 * 26 * 6];      // up to 8 h-rows
  __shared__ float flat_lds[7 * 25 * 10];  // up to 7 stage2-rows
  __shared__ float red[8][10];

  const int bq = blockIdx.x;
  const int b = bq >> 2;
  const int r = bq & 3;
  const int s0 = (r == 0) ? 0 : (1 + 6 * r);  // {0,7,13,19}
  const int ns = (r == 0) ? 7 : 6;            // stage2 rows in quarter
  const int nh = ns + 1;                      // h rows incl. halo

  const int tid = threadIdx.x;
  const int lane = tid & 63;
  const int wv = tid >> 6;  // 0..7
  const int col = lane & 15, q = lane >> 4;

  // ---- B1 fragments -> registers (64 VGPR) ----
  intx4 bfr1[16];
  const intx4* bsrc1 = (const intx4*)bsw1;
#pragma unroll
  for (int c = 0; c < 16; ++c) bfr1[c] = bsrc1[c * 64 + lane];

  // ---- Stage 1 over quarter: nh*26 pixels, wave-strided 16-pixel tiles ----
  const int npix1 = nh * 26;
  const int tiles1 = (npix1 + 15) >> 4;
  const float2* x2 = (const float2*)x + b * 784;
#pragma unroll 1
  for (int tile = wv; tile < tiles1; tile += 8) {
    const int p_raw = tile * 16 + col;
    const int p = p_raw < npix1 ? p_raw : npix1 - 1;  // clamp for addressing
    const int il = p / 26, jj = p - il * 26;          // il: local h row
    const int gi = s0 + il;                           // global h row

    float xv[9][2];
#pragma unroll
    for (int di = 0; di < 3; ++di)
#pragma unroll
      for (int dj = 0; dj < 3; ++dj) {
        float2 v = x2[(gi + di) * 28 + (jj + dj)];
        xv[di * 3 + dj][0] = v.x;
        xv[di * 3 + dj][1] = v.y;
      }

    float w3[8];
#pragma unroll
    for (int j = 0; j < 8; ++j)
      w3[j] = xv[6][(j >> 2) & 1] * xv[7][(j >> 1) & 1] * xv[8][j & 1];

    const float wq = xv[4][(q >> 1) & 1] * xv[5][q & 1];
    float t01[4], t23[4];
#pragma unroll
    for (int a = 0; a < 2; ++a)
#pragma unroll
      for (int d = 0; d < 2; ++d) {
        t01[a * 2 + d] = xv[0][a] * xv[1][d];
        t23[a * 2 + d] = xv[2][a] * xv[3][d] * wq;
      }

    floatx4 acc0 = {0.f, 0.f, 0.f, 0.f};
    floatx4 acc1 = {0.f, 0.f, 0.f, 0.f};
#pragma unroll
    for (int c = 0; c < 16; ++c) {
      Frag bf;
      bf.i = bfr1[c];
      const float w = t01[c >> 2] * t23[c & 3];
      Frag af;
      af.i.x = pk_bf16(w * w3[0], w * w3[1]);
      af.i.y = pk_bf16(w * w3[2], w * w3[3]);
      af.i.z = pk_bf16(w * w3[4], w * w3[5]);
      af.i.w = pk_bf16(w * w3[6], w * w3[7]);
      if (c & 1)
        acc1 = __builtin_amdgcn_mfma_f32_16x16x32_bf16(af.s, bf.s, acc1, 0, 0, 0);
      else
        acc0 = __builtin_amdgcn_mfma_f32_16x16x32_bf16(af.s, bf.s, acc0, 0, 0, 0);
    }
    const floatx4 acc = acc0 + acc1;
    if (col < 6) {
#pragma unroll
      for (int rr = 0; rr < 4; ++rr) {
        const int pp = tile * 16 + q * 4 + rr;
        if (pp < npix1) h_lds[pp * 6 + col] = acc[rr];
      }
    }
  }

  // ---- B2 fragments -> registers (bfr1 dead, regs reused) ----
  intx4 bfr2[45];
  const intx4* bsrc2 = (const intx4*)bsw2;
#pragma unroll
  for (int c = 0; c < 45; ++c) bfr2[c] = bsrc2[c * 64 + lane];

  __syncthreads();  // h_lds complete

  // ---- Stage 2 over quarter: ns*25 pixels, wave-strided ----
  const int npix2 = ns * 25;
  const int tiles2 = (npix2 + 15) >> 4;
#pragma unroll 1
  for (int tile = wv; tile < tiles2; tile += 8) {
    const int p_raw = tile * 16 + col;
    const int p = p_raw < npix2 ? p_raw : npix2 - 1;
    const int il = p / 25, jj = p - il * 25;  // il: local stage2 row
    const int hbase = (il * 26 + jj) * 6;     // h local row == il

    float h00[6], h01[6], h10[6], h11[6];
#pragma unroll
    for (int t = 0; t < 6; ++t) {
      h00[t] = h_lds[hbase + t];
      h01[t] = h_lds[hbase + 6 + t];
      h10[t] = h_lds[hbase + 156 + t];
      h11[t] = h_lds[hbase + 162 + t];
    }

    floatx4 acc0 = {0.f, 0.f, 0.f, 0.f};
    floatx4 acc1 = {0.f, 0.f, 0.f, 0.f};
#pragma unroll
    for (int d = 0; d < 9; ++d) {  // chunk c = 5d + e; m = 9q + d
      const int m = 9 * q + d;
      const int ia = (m * 43) >> 8;  // m/6 exact for m < 54
      const int ic = m - ia * 6;
      const float p01 = sel6(h00, ia) * sel6(h01, ic);
      float ph[6];
#pragma unroll
      for (int a = 0; a < 6; ++a) ph[a] = p01 * h10[a];
#pragma unroll
      for (int e = 0; e < 5; ++e) {
        Frag bf;
        bf.i = bfr2[d * 5 + e];
        const int n0 = 8 * e;
        float av[8];
#pragma unroll
        for (int j = 0; j < 8; ++j) {
          const int n = n0 + j;  // compile-time after unroll
          av[j] = (n < 36) ? ph[n / 6] * h11[n % 6] : 0.0f;
        }
        Frag af;
        af.i.x = pk_bf16(av[0], av[1]);
        af.i.y = pk_bf16(av[2], av[3]);
        af.i.z = pk_bf16(av[4], av[5]);
        af.i.w = pk_bf16(av[6], av[7]);
        if (e & 1)
          acc1 = __builtin_amdgcn_mfma_f32_16x16x32_bf16(af.s, bf.s, acc1, 0, 0, 0);
        else
          acc0 = __builtin_amdgcn_mfma_f32_16x16x32_bf16(af.s, bf.s, acc0, 0, 0, 0);
      }
    }
    const floatx4 acc = acc0 + acc1;
    if (col < 10) {
#pragma unroll
      for (int rr = 0; rr < 4; ++rr) {
        const int pp = tile * 16 + q * 4 + rr;
        if (pp < npix2) flat_lds[pp * 10 + col] = acc[rr];
      }
    }
  }
  __syncthreads();  // flat_lds complete

  // ---- Linear partial: sum over this quarter's flat elements ----
  const int nf = npix2 * 10;       // 1750 or 1500
  const int fg0 = s0 * 250;        // global flat offset of quarter
  float acc[10];
#pragma unroll
  for (int o = 0; o < 10; ++o) acc[o] = 0.0f;
  for (int f = tid; f < nf; f += 512) {
    const float v = flat_lds[f];
#pragma unroll
    for (int o = 0; o < 10; ++o) acc[o] += v * W[o * 6250 + fg0 + f];
  }
#pragma unroll
  for (int o = 0; o < 10; ++o) {
#pragma unroll
    for (int s = 32; s > 0; s >>= 1) acc[o] += __shfl_xor(acc[o], s, 64);
  }
  if (lane == 0) {
#pragma unroll
    for (int o = 0; o < 10; ++o) red[wv][o] = acc[o];
  }
  __syncthreads();
  if (tid < 10) {
    float v = (r == 0) ? bias[tid] : 0.0f;
#pragma unroll
    for (int ww = 0; ww < 8; ++ww) v += red[ww][tid];
    atomicAdd(&out[b * 10 + tid], v);
  }
}

// ---------------------------------------------------------------------------
extern "C" void kernel_launch(void* const* d_in, const int* in_sizes, int n_in,
                              void* d_out, int out_size, void* d_ws,
                              size_t ws_size, hipStream_t stream) {
  const float* x = (const float*)d_in[0];     // (128,28,28,2)
  const float* eps0 = (const float*)d_in[1];  // (6,512)
  const float* eps1 = (const float*)d_in[2];  // (10,1296)
  const float* W = (const float*)d_in[3];     // (10,6250)
  const float* bias = (const float*)d_in[4];  // (10,)
  float* out = (float*)d_out;                 // (128,10)

  char* wsb = (char*)d_ws;
  unsigned short* bsw1 = (unsigned short*)wsb;            // 16384 B
  unsigned short* bsw2 = (unsigned short*)(wsb + 16384);  // 46080 B

  hipLaunchKernelGGL(prep_kernel, dim3(122), dim3(256), 0, stream, eps0, eps1,
                     bsw1, bsw2, out);
  hipLaunchKernelGGL(fused_kernel, dim3(512), dim3(512), 0, stream, x, bsw1,
                     bsw2, W, bias, out);
}

// Round 10
// 116.400 us; speedup vs baseline: 1.0242x; 1.0242x over previous
//
#include <hip/hip_runtime.h>
#include <hip/hip_bf16.h>
#include <stdint.h>

typedef __attribute__((ext_vector_type(8))) short short8;
typedef __attribute__((ext_vector_type(4))) float floatx4;
typedef __attribute__((ext_vector_type(4))) int intx4;

// ---------------------------------------------------------------------------
// Threefry-2x32 (20 rounds), bit-exact vs JAX (verified r2: absmax 0.0).
// ---------------------------------------------------------------------------
__device__ __forceinline__ void threefry2x32(uint32_t k0, uint32_t k1,
                                             uint32_t& x0, uint32_t& x1) {
  const uint32_t ks2 = k0 ^ k1 ^ 0x1BD11BDAu;
  uint32_t ks[3] = {k0, k1, ks2};
  const int rot[8] = {13, 15, 26, 6, 17, 29, 16, 24};
  x0 += ks[0];
  x1 += ks[1];
#pragma unroll
  for (int i = 0; i < 5; ++i) {
#pragma unroll
    for (int j = 0; j < 4; ++j) {
      const int r = rot[(i & 1) * 4 + j];
      x0 += x1;
      x1 = (x1 << r) | (x1 >> (32 - r));
      x1 ^= x0;
    }
    x0 += ks[(i + 1) % 3];
    x1 += ks[(i + 2) % 3] + (uint32_t)(i + 1);
  }
}

__device__ __forceinline__ float dropmask(int core, int e, float v) {
  uint32_t f0 = 0u, f1 = (uint32_t)core;
  threefry2x32(0u, 42u, f0, f1);
  uint32_t a = 0u, b = (uint32_t)e;
  threefry2x32(f0, f1, a, b);
  uint32_t bits = a ^ b;
  float u = __uint_as_float((bits >> 9) | 0x3F800000u) - 1.0f;
  float m = (u < 0.8f) ? 1.0f : 0.0f;
  return v * m / 0.8f;
}

__device__ __forceinline__ unsigned short f2bf(float f) {  // RNE
  uint32_t u = __float_as_uint(f);
  uint32_t r = u + 0x7fffu + ((u >> 16) & 1u);
  return (unsigned short)(r >> 16);
}

union B2I { __hip_bfloat162 b; int i; };
__device__ __forceinline__ int pk_bf16(float lo, float hi) {
  B2I u;
  u.b = __float22bfloat162_rn(make_float2(lo, hi));
  return u.i;
}
union Frag { intx4 i; short8 s; };

// ---------------------------------------------------------------------------
// Prep: masked bf16 B matrices, pre-swizzled into MFMA B-fragment order
// (verified r3-r9). stage1: k = c*32+q*8+j (c<16). stage2: t=45q+c, m=t/5,
// nk=8*(t%5)+j (c<45, K'=1440, zeros for nk>=36 or invalid col).
// Also zero-inits out (fused kernel accumulates with atomics).
// ---------------------------------------------------------------------------
__global__ void prep_kernel(const float* __restrict__ eps0,
                            const float* __restrict__ eps1,
                            unsigned short* __restrict__ bsw1,
                            unsigned short* __restrict__ bsw2,
                            float* __restrict__ out) {
  int idx = blockIdx.x * 256 + threadIdx.x;  // grid exactly 31232
  if (idx < 1280) out[idx] = 0.0f;
  if (idx < 8192) {
    int j = idx & 7, L = (idx >> 3) & 63, c = idx >> 9;
    int o = L & 15, q = L >> 4;
    int k = c * 32 + q * 8 + j;
    float v = 0.0f;
    if (o < 6) {
      int e = o * 512 + k;
      v = dropmask(0, e, eps0[e]);
    }
    bsw1[idx] = f2bf(v);
  } else {
    int t2 = idx - 8192;  // < 23040 = 45*512
    int j = t2 & 7, L = (t2 >> 3) & 63, c = t2 >> 9;
    int o = L & 15, q = L >> 4;
    int t = 45 * q + c;
    int m = t / 5, nk = 8 * (t % 5) + j;
    float v = 0.0f;
    if (o < 10 && nk < 36) {
      int e = o * 1296 + m * 36 + nk;
      v = dropmask(1, e, eps1[e]);
    }
    bsw2[t2] = f2bf(v);
  }
}

// 6-way select, cndmask chain (runtime k, constant element indices)
__device__ __forceinline__ float sel6(const float a[6], int k) {
  float r = a[0];
  r = (k == 1) ? a[1] : r;
  r = (k == 2) ? a[2] : r;
  r = (k == 3) ? a[3] : r;
  r = (k == 4) ? a[4] : r;
  r = (k == 5) ? a[5] : r;
  return r;
}

// ---------------------------------------------------------------------------
// Fused kernel: 4 blocks/image (grid 512 = 2 blocks/CU), 256 thr = 4 waves.
// Key structure vs r9: B2 lives in LDS (staged once per block), and every
// B access (ds_read or register) is amortized over T tiles' MFMAs:
//   stage1: B1 register-resident (64 VGPR), T=4 tiles per wave, 0 loads/loop
//   stage2: per chunk ONE ds_read_b128 feeds T=3 tiles (36 VALU + 3 MFMA)
// Per-tile state is small (29 VGPR/tile) -> truly register-resident at the
// 256-VGPR cap from __launch_bounds__(256,2).
// ---------------------------------------------------------------------------
__global__ __launch_bounds__(256, 2) void fused_kernel(
    const float* __restrict__ x, const unsigned short* __restrict__ bsw1,
    const unsigned short* __restrict__ bsw2, const float* __restrict__ W,
    const float* __restrict__ bias, float* __restrict__ out) {
  __shared__ intx4 B2s[2880];          // 46080 B
  __shared__ float h_lds[208 * 6];     // 4992 B (up to 8 h-rows)
  __shared__ float flat_lds[175 * 10]; // 7000 B (up to 7 stage2-rows)
  __shared__ float red[4][10];

  const int bq = blockIdx.x;
  const int b = bq >> 2;
  const int r = bq & 3;
  const int s0 = (r == 0) ? 0 : (1 + 6 * r);  // {0,7,13,19}
  const int ns = (r == 0) ? 7 : 6;            // stage2 rows in quarter
  const int nh = ns + 1;                      // h rows incl. halo

  const int tid = threadIdx.x;
  const int lane = tid & 63;
  const int wv = tid >> 6;  // 0..3
  const int col = lane & 15, q = lane >> 4;

  // ---- stage B2 into LDS (coalesced; consumed after the next barrier) ----
  {
    const intx4* src = (const intx4*)bsw2;
    for (int t = tid; t < 2880; t += 256) B2s[t] = src[t];
  }

  // ---- B1 fragments -> registers (64 VGPR) ----
  intx4 bfr1[16];
  const intx4* bsrc1 = (const intx4*)bsw1;
#pragma unroll
  for (int c = 0; c < 16; ++c) bfr1[c] = bsrc1[c * 64 + lane];

  // ---- Stage 1: T=4 tiles per wave over nh*26 pixels ----
  const int npix1 = nh * 26;
  const int tiles1 = (npix1 + 15) >> 4;  // 13 (r=0) or 12
  const float2* x2 = (const float2*)x + b * 784;
  float w3v[4][8], t01v[4][4], t23v[4][4];
#pragma unroll
  for (int t = 0; t < 4; ++t) {
    const int tile = wv + 4 * t;
    const int tt = (tile < tiles1) ? tile : (tiles1 - 1);  // clamp
    const int p_raw = tt * 16 + col;
    const int p = (p_raw < npix1) ? p_raw : (npix1 - 1);
    const int il = p / 26, jj = p - il * 26;
    const int gi = s0 + il;

    float xv[9][2];
#pragma unroll
    for (int di = 0; di < 3; ++di)
#pragma unroll
      for (int dj = 0; dj < 3; ++dj) {
        float2 v = x2[(gi + di) * 28 + (jj + dj)];
        xv[di * 3 + dj][0] = v.x;
        xv[di * 3 + dj][1] = v.y;
      }
#pragma unroll
    for (int j = 0; j < 8; ++j)
      w3v[t][j] = xv[6][(j >> 2) & 1] * xv[7][(j >> 1) & 1] * xv[8][j & 1];
    const float wq = xv[4][(q >> 1) & 1] * xv[5][q & 1];
#pragma unroll
    for (int a = 0; a < 2; ++a)
#pragma unroll
      for (int d = 0; d < 2; ++d) {
        t01v[t][a * 2 + d] = xv[0][a] * xv[1][d];
        t23v[t][a * 2 + d] = xv[2][a] * xv[3][d] * wq;
      }
  }

  floatx4 s1a[4], s1b[4];
#pragma unroll
  for (int t = 0; t < 4; ++t) {
    s1a[t] = floatx4{0.f, 0.f, 0.f, 0.f};
    s1b[t] = floatx4{0.f, 0.f, 0.f, 0.f};
  }
#pragma unroll
  for (int c = 0; c < 16; ++c) {
    Frag bf;
    bf.i = bfr1[c];
#pragma unroll
    for (int t = 0; t < 4; ++t) {
      const float w = t01v[t][c >> 2] * t23v[t][c & 3];
      Frag af;
      af.i.x = pk_bf16(w * w3v[t][0], w * w3v[t][1]);
      af.i.y = pk_bf16(w * w3v[t][2], w * w3v[t][3]);
      af.i.z = pk_bf16(w * w3v[t][4], w * w3v[t][5]);
      af.i.w = pk_bf16(w * w3v[t][6], w * w3v[t][7]);
      if (c & 1)
        s1b[t] = __builtin_amdgcn_mfma_f32_16x16x32_bf16(af.s, bf.s, s1b[t], 0, 0, 0);
      else
        s1a[t] = __builtin_amdgcn_mfma_f32_16x16x32_bf16(af.s, bf.s, s1a[t], 0, 0, 0);
    }
  }
#pragma unroll
  for (int t = 0; t < 4; ++t) {
    const int tile = wv + 4 * t;
    if (tile < tiles1 && col < 6) {
      const floatx4 acc = s1a[t] + s1b[t];
#pragma unroll
      for (int rr = 0; rr < 4; ++rr) {
        const int pp = tile * 16 + q * 4 + rr;
        if (pp < npix1) h_lds[pp * 6 + col] = acc[rr];
      }
    }
  }
  __syncthreads();  // h_lds + B2s complete

  // ---- Stage 2: T=3 tiles per wave over ns*25 pixels ----
  const int npix2 = ns * 25;
  const int tiles2 = (npix2 + 15) >> 4;  // 11 (r=0) or 10
  float P01s[3][9], h10v[3][6], h11v[3][6];
#pragma unroll
  for (int t = 0; t < 3; ++t) {
    const int tile = wv + 4 * t;
    const int tt = (tile < tiles2) ? tile : (tiles2 - 1);
    const int p_raw = tt * 16 + col;
    const int p = (p_raw < npix2) ? p_raw : (npix2 - 1);
    const int il = p / 25, jj = p - il * 25;
    const int hbase = (il * 26 + jj) * 6;
    float h00[6], h01[6];
#pragma unroll
    for (int k = 0; k < 6; ++k) {
      h00[k] = h_lds[hbase + k];
      h01[k] = h_lds[hbase + 6 + k];
      h10v[t][k] = h_lds[hbase + 156 + k];
      h11v[t][k] = h_lds[hbase + 162 + k];
    }
#pragma unroll
    for (int d = 0; d < 9; ++d) {
      const int m = 9 * q + d;
      const int ia = (m * 43) >> 8;  // m/6 exact for m < 54
      const int ic = m - ia * 6;
      P01s[t][d] = sel6(h00, ia) * sel6(h01, ic);
    }
  }

  floatx4 s2a[3], s2b[3];
#pragma unroll
  for (int t = 0; t < 3; ++t) {
    s2a[t] = floatx4{0.f, 0.f, 0.f, 0.f};
    s2b[t] = floatx4{0.f, 0.f, 0.f, 0.f};
  }
#pragma unroll
  for (int d = 0; d < 9; ++d) {
    float ph[3][6];
#pragma unroll
    for (int t = 0; t < 3; ++t)
#pragma unroll
      for (int a = 0; a < 6; ++a) ph[t][a] = P01s[t][d] * h10v[t][a];
#pragma unroll
    for (int e = 0; e < 5; ++e) {
      Frag bf;
      bf.i = B2s[(d * 5 + e) * 64 + lane];  // one ds_read_b128, T tiles use it
#pragma unroll
      for (int t = 0; t < 3; ++t) {
        float av[8];
#pragma unroll
        for (int j = 0; j < 8; ++j) {
          const int n = 8 * e + j;  // compile-time after unroll
          av[j] = (n < 36) ? ph[t][n / 6] * h11v[t][n % 6] : 0.0f;
        }
        Frag af;
        af.i.x = pk_bf16(av[0], av[1]);
        af.i.y = pk_bf16(av[2], av[3]);
        af.i.z = pk_bf16(av[4], av[5]);
        af.i.w = pk_bf16(av[6], av[7]);
        if (e & 1)
          s2b[t] = __builtin_amdgcn_mfma_f32_16x16x32_bf16(af.s, bf.s, s2b[t], 0, 0, 0);
        else
          s2a[t] = __builtin_amdgcn_mfma_f32_16x16x32_bf16(af.s, bf.s, s2a[t], 0, 0, 0);
      }
    }
  }
#pragma unroll
  for (int t = 0; t < 3; ++t) {
    const int tile = wv + 4 * t;
    if (tile < tiles2 && col < 10) {
      const floatx4 acc = s2a[t] + s2b[t];
#pragma unroll
      for (int rr = 0; rr < 4; ++rr) {
        const int pp = tile * 16 + q * 4 + rr;
        if (pp < npix2) flat_lds[pp * 10 + col] = acc[rr];
      }
    }
  }
  __syncthreads();  // flat_lds complete

  // ---- Linear partial over this quarter + atomicAdd ----
  const int nf = npix2 * 10;  // 1750 or 1500
  const int fg0 = s0 * 250;   // global flat offset of quarter
  float acc[10];
#pragma unroll
  for (int o = 0; o < 10; ++o) acc[o] = 0.0f;
  for (int f = tid; f < nf; f += 256) {
    const float v = flat_lds[f];
#pragma unroll
    for (int o = 0; o < 10; ++o) acc[o] += v * W[o * 6250 + fg0 + f];
  }
#pragma unroll
  for (int o = 0; o < 10; ++o) {
#pragma unroll
    for (int s = 32; s > 0; s >>= 1) acc[o] += __shfl_xor(acc[o], s, 64);
  }
  if (lane == 0) {
#pragma unroll
    for (int o = 0; o < 10; ++o) red[wv][o] = acc[o];
  }
  __syncthreads();
  if (tid < 10) {
    float v = (r == 0) ? bias[tid] : 0.0f;
#pragma unroll
    for (int ww = 0; ww < 4; ++ww) v += red[ww][tid];
    atomicAdd(&out[b * 10 + tid], v);
  }
}

// ---------------------------------------------------------------------------
extern "C" void kernel_launch(void* const* d_in, const int* in_sizes, int n_in,
                              void* d_out, int out_size, void* d_ws,
                              size_t ws_size, hipStream_t stream) {
  const float* x = (const float*)d_in[0];     // (128,28,28,2)
  const float* eps0 = (const float*)d_in[1];  // (6,512)
  const float* eps1 = (const float*)d_in[2];  // (10,1296)
  const float* W = (const float*)d_in[3];     // (10,6250)
  const float* bias = (const float*)d_in[4];  // (10,)
  float* out = (float*)d_out;                 // (128,10)

  char* wsb = (char*)d_ws;
  unsigned short* bsw1 = (unsigned short*)wsb;            // 16384 B
  unsigned short* bsw2 = (unsigned short*)(wsb + 16384);  // 46080 B

  hipLaunchKernelGGL(prep_kernel, dim3(122), dim3(256), 0, stream, eps0, eps1,
                     bsw1, bsw2, out);
  hipLaunchKernelGGL(fused_kernel, dim3(512), dim3(256), 0, stream, x, bsw1,
                     bsw2, W, bias, out);
}

// Round 11
// 110.055 us; speedup vs baseline: 1.0833x; 1.0577x over previous
//
#include <hip/hip_runtime.h>
#include <stdint.h>

typedef _Float16 half8 __attribute__((ext_vector_type(8)));
typedef _Float16 half2v __attribute__((ext_vector_type(2)));
typedef __attribute__((ext_vector_type(4))) float floatx4;
typedef __attribute__((ext_vector_type(4))) int intx4;

// ---------------------------------------------------------------------------
// Threefry-2x32 (20 rounds), bit-exact vs JAX (verified r2: absmax 0.0).
// ---------------------------------------------------------------------------
__device__ __forceinline__ void threefry2x32(uint32_t k0, uint32_t k1,
                                             uint32_t& x0, uint32_t& x1) {
  const uint32_t ks2 = k0 ^ k1 ^ 0x1BD11BDAu;
  uint32_t ks[3] = {k0, k1, ks2};
  const int rot[8] = {13, 15, 26, 6, 17, 29, 16, 24};
  x0 += ks[0];
  x1 += ks[1];
#pragma unroll
  for (int i = 0; i < 5; ++i) {
#pragma unroll
    for (int j = 0; j < 4; ++j) {
      const int r = rot[(i & 1) * 4 + j];
      x0 += x1;
      x1 = (x1 << r) | (x1 >> (32 - r));
      x1 ^= x0;
    }
    x0 += ks[(i + 1) % 3];
    x1 += ks[(i + 2) % 3] + (uint32_t)(i + 1);
  }
}

__device__ __forceinline__ float dropmask(int core, int e, float v) {
  uint32_t f0 = 0u, f1 = (uint32_t)core;
  threefry2x32(0u, 42u, f0, f1);
  uint32_t a = 0u, b = (uint32_t)e;
  threefry2x32(f0, f1, a, b);
  uint32_t bits = a ^ b;
  float u = __uint_as_float((bits >> 9) | 0x3F800000u) - 1.0f;
  float m = (u < 0.8f) ? 1.0f : 0.0f;
  return v * m / 0.8f;
}

union H2U { _Float16 h; unsigned short s; };
__device__ __forceinline__ unsigned short f2h(float f) {  // RNE fp32->fp16
  H2U u;
  u.h = (_Float16)f;
  return u.s;
}

union FragH { intx4 i; half8 h; half2v h2[4]; };

// ---------------------------------------------------------------------------
// Prep: masked fp16 B matrices in MFMA B-fragment order.
//   bsw1 (stage1): idx=(c<16, lane, j): k = c*32 + q*8 + j, col o = lane&15
//   bsw2 (stage2): idx=(c<54, lane, j): m = 9q + c/6, a = c%6, n = 6a + j
//                  (j>=6 pad -> 0). K' = 54*32 = 1728.
// Mask PRNG identical to r2-r10 (bit-exact). Also zero-inits out.
// ---------------------------------------------------------------------------
__global__ void prep_kernel(const float* __restrict__ eps0,
                            const float* __restrict__ eps1,
                            unsigned short* __restrict__ bsw1,
                            unsigned short* __restrict__ bsw2,
                            float* __restrict__ out) {
  int idx = blockIdx.x * 256 + threadIdx.x;  // 35840 threads total
  if (idx < 1280) out[idx] = 0.0f;
  if (idx < 8192) {
    int j = idx & 7, L = (idx >> 3) & 63, c = idx >> 9;
    int o = L & 15, q = L >> 4;
    int k = c * 32 + q * 8 + j;
    float v = 0.0f;
    if (o < 6) {
      int e = o * 512 + k;
      v = dropmask(0, e, eps0[e]);
    }
    bsw1[idx] = f2h(v);
  } else if (idx < 35840) {
    int t2 = idx - 8192;  // < 27648 = 54*512
    int j = t2 & 7, L = (t2 >> 3) & 63, c = t2 >> 9;
    int o = L & 15, q = L >> 4;
    int m = 9 * q + c / 6;
    int a = c % 6;
    int n = 6 * a + j;
    float v = 0.0f;
    if (o < 10 && j < 6) {
      int e = o * 1296 + m * 36 + n;
      v = dropmask(1, e, eps1[e]);
    }
    bsw2[t2] = f2h(v);
  }
}

// 6-way select, cndmask chain (runtime k, constant element indices)
__device__ __forceinline__ float sel6(const float a[6], int k) {
  float r = a[0];
  r = (k == 1) ? a[1] : r;
  r = (k == 2) ? a[2] : r;
  r = (k == 3) ? a[3] : r;
  r = (k == 4) ? a[4] : r;
  r = (k == 5) ? a[5] : r;
  return r;
}

// ---------------------------------------------------------------------------
// Fused kernel: 8 blocks/image (grid 1024, 256 thr = 4 waves, 2 blocks/CU
// resident, 4 queued). fp16 MFMA; A-fragments built with native v_pk_mul_f16
// (no pack-conversion in the loop). B2 staged in LDS per block; B1 in regs.
// Piece r: stage2 rows s0..s0+ns (r=0: 4 rows, else 3), h rows +1 halo.
// ---------------------------------------------------------------------------
__global__ __launch_bounds__(256, 2) void fused_kernel(
    const float* __restrict__ x, const unsigned short* __restrict__ bsw1,
    const unsigned short* __restrict__ bsw2, const float* __restrict__ W,
    const float* __restrict__ bias, float* __restrict__ out) {
  __shared__ intx4 B2s[3456];        // 54 chunks * 64 lanes * 16B = 55296 B
  __shared__ float h_lds[5 * 156];   // up to 5 h-rows * 26 * 6
  __shared__ float flat_lds[1000];   // up to 4 rows * 25 * 10
  __shared__ float red[4][10];

  const int bq = blockIdx.x;
  const int b = bq >> 3;
  const int r = bq & 7;
  const int s0 = (r == 0) ? 0 : (1 + 3 * r);  // {0,4,7,10,13,16,19,22}
  const int ns = (r == 0) ? 4 : 3;            // stage2 rows in piece
  const int nh = ns + 1;                      // h rows incl. halo

  const int tid = threadIdx.x;
  const int lane = tid & 63;
  const int wv = tid >> 6;  // 0..3
  const int col = lane & 15, q = lane >> 4;

  // ---- stage B2 into LDS (coalesced; consumed after barrier) ----
  {
    const intx4* src = (const intx4*)bsw2;
    for (int t = tid; t < 3456; t += 256) B2s[t] = src[t];
  }

  // ---- B1 fragments -> registers (64 VGPR) ----
  intx4 bfr1[16];
  const intx4* bsrc1 = (const intx4*)bsw1;
#pragma unroll
  for (int c = 0; c < 16; ++c) bfr1[c] = bsrc1[c * 64 + lane];

  // ---- Stage 1: tiles of 16 pixels over nh*26, wave-strided ----
  const int npix1 = nh * 26;             // 130 or 104
  const int tiles1 = (npix1 + 15) >> 4;  // 9 or 7
  const float2* x2 = (const float2*)x + b * 784;
#pragma unroll 1
  for (int tile = wv; tile < tiles1; tile += 4) {
    const int p_raw = tile * 16 + col;
    const int p = (p_raw < npix1) ? p_raw : (npix1 - 1);  // clamp
    const int il = p / 26, jj = p - il * 26;
    const int gi = s0 + il;

    float xv[9][2];
#pragma unroll
    for (int di = 0; di < 3; ++di)
#pragma unroll
      for (int dj = 0; dj < 3; ++dj) {
        float2 v = x2[(gi + di) * 28 + (jj + dj)];
        xv[di * 3 + dj][0] = v.x;
        xv[di * 3 + dj][1] = v.y;
      }

    // w3 packed to fp16 pairs once per tile
    half2v w3p[4];
#pragma unroll
    for (int p2 = 0; p2 < 4; ++p2) {
      const int j0 = 2 * p2, j1 = 2 * p2 + 1;
      const float a0 = xv[6][(j0 >> 2) & 1] * xv[7][(j0 >> 1) & 1] * xv[8][j0 & 1];
      const float a1 = xv[6][(j1 >> 2) & 1] * xv[7][(j1 >> 1) & 1] * xv[8][j1 & 1];
      w3p[p2] = half2v{(_Float16)a0, (_Float16)a1};
    }

    const float wq = xv[4][(q >> 1) & 1] * xv[5][q & 1];
    float t01[4], t23[4];
#pragma unroll
    for (int a = 0; a < 2; ++a)
#pragma unroll
      for (int d = 0; d < 2; ++d) {
        t01[a * 2 + d] = xv[0][a] * xv[1][d];
        t23[a * 2 + d] = xv[2][a] * xv[3][d] * wq;
      }

    floatx4 acc0 = {0.f, 0.f, 0.f, 0.f};
    floatx4 acc1 = {0.f, 0.f, 0.f, 0.f};
#pragma unroll
    for (int c = 0; c < 16; ++c) {
      FragH bf;
      bf.i = bfr1[c];
      const _Float16 wh = (_Float16)(t01[c >> 2] * t23[c & 3]);
      const half2v w2 = {wh, wh};
      FragH af;
      af.h2[0] = w2 * w3p[0];
      af.h2[1] = w2 * w3p[1];
      af.h2[2] = w2 * w3p[2];
      af.h2[3] = w2 * w3p[3];
      if (c & 1)
        acc1 = __builtin_amdgcn_mfma_f32_16x16x32_f16(af.h, bf.h, acc1, 0, 0, 0);
      else
        acc0 = __builtin_amdgcn_mfma_f32_16x16x32_f16(af.h, bf.h, acc0, 0, 0, 0);
    }
    const floatx4 acc = acc0 + acc1;
    if (col < 6) {
#pragma unroll
      for (int rr = 0; rr < 4; ++rr) {
        const int pp = tile * 16 + q * 4 + rr;
        if (pp < npix1) h_lds[pp * 6 + col] = acc[rr];
      }
    }
  }
  __syncthreads();  // h_lds + B2s complete

  // ---- Stage 2: tiles of 16 pixels over ns*25, wave-strided ----
  const int npix2 = ns * 25;             // 100 or 75
  const int tiles2 = (npix2 + 15) >> 4;  // 7 or 5
#pragma unroll 1
  for (int tile = wv; tile < tiles2; tile += 4) {
    const int p_raw = tile * 16 + col;
    const int p = (p_raw < npix2) ? p_raw : (npix2 - 1);
    const int il = p / 25, jj = p - il * 25;
    const int hbase = (il * 26 + jj) * 6;

    float h00[6], h01[6], h10[6], h11f[6];
    {
      const float2* ha = (const float2*)&h_lds[hbase];
      const float2* hb = (const float2*)&h_lds[hbase + 156];
#pragma unroll
      for (int t = 0; t < 3; ++t) {
        float2 v0 = ha[t], v1 = ha[t + 3], v2 = hb[t], v3 = hb[t + 3];
        h00[2 * t] = v0.x; h00[2 * t + 1] = v0.y;
        h01[2 * t] = v1.x; h01[2 * t + 1] = v1.y;
        h10[2 * t] = v2.x; h10[2 * t + 1] = v2.y;
        h11f[2 * t] = v3.x; h11f[2 * t + 1] = v3.y;
      }
    }
    // h11 packed fp16 pairs once per tile
    half2v h11p[3];
#pragma unroll
    for (int t = 0; t < 3; ++t)
      h11p[t] = half2v{(_Float16)h11f[2 * t], (_Float16)h11f[2 * t + 1]};

    float P01s[9];
#pragma unroll
    for (int d = 0; d < 9; ++d) {
      const int m = 9 * q + d;
      const int ia = (m * 43) >> 8;  // m/6 exact for m < 54
      const int ic = m - ia * 6;
      P01s[d] = sel6(h00, ia) * sel6(h01, ic);
    }

    floatx4 acc0 = {0.f, 0.f, 0.f, 0.f};
    floatx4 acc1 = {0.f, 0.f, 0.f, 0.f};
#pragma unroll
    for (int c = 0; c < 54; ++c) {  // chunk c: m = 9q + c/6, a = c%6
      FragH bf;
      bf.i = B2s[c * 64 + lane];
      const float pha = P01s[c / 6] * h10[c % 6];  // compile-time indices
      const _Float16 ph = (_Float16)pha;
      const half2v p2 = {ph, ph};
      FragH af;
      af.h2[0] = p2 * h11p[0];
      af.h2[1] = p2 * h11p[1];
      af.h2[2] = p2 * h11p[2];
      af.h2[3] = half2v{(_Float16)0.f, (_Float16)0.f};  // n pad
      if (c & 1)
        acc1 = __builtin_amdgcn_mfma_f32_16x16x32_f16(af.h, bf.h, acc1, 0, 0, 0);
      else
        acc0 = __builtin_amdgcn_mfma_f32_16x16x32_f16(af.h, bf.h, acc0, 0, 0, 0);
    }
    const floatx4 acc = acc0 + acc1;
    if (col < 10) {
#pragma unroll
      for (int rr = 0; rr < 4; ++rr) {
        const int pp = tile * 16 + q * 4 + rr;
        if (pp < npix2) flat_lds[pp * 10 + col] = acc[rr];
      }
    }
  }
  __syncthreads();  // flat_lds complete

  // ---- Linear partial over this piece + atomicAdd ----
  const int nf = npix2 * 10;  // 1000 or 750
  const int fg0 = s0 * 250;
  float acc[10];
#pragma unroll
  for (int o = 0; o < 10; ++o) acc[o] = 0.0f;
  for (int f = tid; f < nf; f += 256) {
    const float v = flat_lds[f];
#pragma unroll
    for (int o = 0; o < 10; ++o) acc[o] += v * W[o * 6250 + fg0 + f];
  }
#pragma unroll
  for (int o = 0; o < 10; ++o) {
#pragma unroll
    for (int s = 32; s > 0; s >>= 1) acc[o] += __shfl_xor(acc[o], s, 64);
  }
  if (lane == 0) {
#pragma unroll
    for (int o = 0; o < 10; ++o) red[wv][o] = acc[o];
  }
  __syncthreads();
  if (tid < 10) {
    float v = (r == 0) ? bias[tid] : 0.0f;
#pragma unroll
    for (int ww = 0; ww < 4; ++ww) v += red[ww][tid];
    atomicAdd(&out[b * 10 + tid], v);
  }
}

// ---------------------------------------------------------------------------
extern "C" void kernel_launch(void* const* d_in, const int* in_sizes, int n_in,
                              void* d_out, int out_size, void* d_ws,
                              size_t ws_size, hipStream_t stream) {
  const float* x = (const float*)d_in[0];     // (128,28,28,2)
  const float* eps0 = (const float*)d_in[1];  // (6,512)
  const float* eps1 = (const float*)d_in[2];  // (10,1296)
  const float* W = (const float*)d_in[3];     // (10,6250)
  const float* bias = (const float*)d_in[4];  // (10,)
  float* out = (float*)d_out;                 // (128,10)

  char* wsb = (char*)d_ws;
  unsigned short* bsw1 = (unsigned short*)wsb;            // 16384 B
  unsigned short* bsw2 = (unsigned short*)(wsb + 16384);  // 55296 B

  hipLaunchKernelGGL(prep_kernel, dim3(140), dim3(256), 0, stream, eps0, eps1,
                     bsw1, bsw2, out);
  hipLaunchKernelGGL(fused_kernel, dim3(1024), dim3(256), 0, stream, x, bsw1,
                     bsw2, W, bias, out);
}